// Round 16
// baseline (2568.161 us; speedup 1.0000x reference)
//
#include <hip/hip_runtime.h>
#include <hip/hip_bf16.h>
#include <math.h>

#define D_EMB  1024
#define T_TOK  1024
#define T1_TOK 768
#define T2_TOK 256
#define HMLP   4096
#define NLAYER 12
#define VCLS   512

typedef __attribute__((ext_vector_type(8))) short          short8; // 8 bf16
typedef __attribute__((ext_vector_type(4))) float          f32x4;
typedef __attribute__((ext_vector_type(4))) unsigned short us4;
typedef unsigned short us;

__device__ __forceinline__ us f2bf(float f) {
    union { float f; unsigned int u; } c; c.f = f;
    unsigned int u = c.u;
    return (us)((u + 0x7FFFu + ((u >> 16) & 1u)) >> 16); // RNE
}

__device__ __forceinline__ float bf2f(us u) {
    union { unsigned int i; float f; } c; c.i = ((unsigned int)u) << 16;
    return c.f;
}

__device__ __forceinline__ void gld_lds16(const us* g, us* l) {
    __builtin_amdgcn_global_load_lds(
        (__attribute__((address_space(1))) void*)g,
        (__attribute__((address_space(3))) void*)l, 16, 0, 0);
}

// ---------------------------------------------------------------------------
__global__ __launch_bounds__(256)
void embed_kernel(const int* __restrict__ xt, const int* __restrict__ zi,
                  const float* __restrict__ pos, const float* __restrict__ temb,
                  const float* __restrict__ iemb, float* __restrict__ H)
{
    const long idx = (long)blockIdx.x * 256 + threadIdx.x;
    const long e   = idx * 4;
    const int  dd  = (int)(e & (D_EMB - 1));
    const long bt  = e >> 10;
    const int  t   = (int)(bt & (T_TOK - 1));
    const int  b   = (int)(bt >> 10);
    const float* src;
    if (t < T2_TOK) src = iemb + (long)zi[b * T2_TOK + t] * D_EMB + dd;
    else            src = temb + (long)xt[b * T1_TOK + (t - T2_TOK)] * D_EMB + dd;
    float4 sv = *(const float4*)src;
    float4 pv = *(const float4*)(pos + (long)t * D_EMB + dd);
    float4 o; o.x = sv.x + pv.x; o.y = sv.y + pv.y; o.z = sv.z + pv.z; o.w = sv.w + pv.w;
    *(float4*)(H + e) = o;
}

// ---------------------------------------------------------------------------
__global__ __launch_bounds__(256)
void ln_kernel(const float* __restrict__ X, const float* __restrict__ g,
               const float* __restrict__ b, us* __restrict__ Y)
{
    const long row = blockIdx.x;
    const int  tid = threadIdx.x;
    float4 v = *(const float4*)(X + row * D_EMB + tid * 4);
    float s = v.x + v.y + v.z + v.w;
    float q = v.x*v.x + v.y*v.y + v.z*v.z + v.w*v.w;
    #pragma unroll
    for (int o = 32; o >= 1; o >>= 1) { s += __shfl_down(s, o); q += __shfl_down(q, o); }
    __shared__ float rs[4], rq[4];
    const int w = tid >> 6;
    if ((tid & 63) == 0) { rs[w] = s; rq[w] = q; }
    __syncthreads();
    s = rs[0] + rs[1] + rs[2] + rs[3];
    q = rq[0] + rq[1] + rq[2] + rq[3];
    const float mean = s * (1.0f / D_EMB);
    const float var  = q * (1.0f / D_EMB) - mean * mean;
    const float rstd = rsqrtf(var + 1e-5f);
    float4 gg = *(const float4*)(g + tid * 4);
    float4 bb = *(const float4*)(b + tid * 4);
    us4 o;
    o.x = f2bf((v.x - mean) * rstd * gg.x + bb.x);
    o.y = f2bf((v.y - mean) * rstd * gg.y + bb.y);
    o.z = f2bf((v.z - mean) * rstd * gg.z + bb.z);
    o.w = f2bf((v.w - mean) * rstd * gg.w + bb.w);
    *(us4*)(Y + row * D_EMB + tid * 4) = o;
}

// ---------------------------------------------------------------------------
__global__ __launch_bounds__(256)
void softmax_kernel(const us* __restrict__ S, us* __restrict__ P)
{
    const long row = blockIdx.x;
    const int  tid = threadIdx.x;
    us4 v = *(const us4*)(S + row * T_TOK + tid * 4);
    float a = bf2f(v.x), b = bf2f(v.y), c = bf2f(v.z), d = bf2f(v.w);
    float mx = fmaxf(fmaxf(a, b), fmaxf(c, d));
    #pragma unroll
    for (int o = 32; o >= 1; o >>= 1) mx = fmaxf(mx, __shfl_down(mx, o));
    __shared__ float rm[4], rsum[4];
    const int w = tid >> 6;
    if ((tid & 63) == 0) rm[w] = mx;
    __syncthreads();
    mx = fmaxf(fmaxf(rm[0], rm[1]), fmaxf(rm[2], rm[3]));
    float e0 = expf(a - mx), e1 = expf(b - mx), e2 = expf(c - mx), e3 = expf(d - mx);
    float s = e0 + e1 + e2 + e3;
    #pragma unroll
    for (int o = 32; o >= 1; o >>= 1) s += __shfl_down(s, o);
    if ((tid & 63) == 0) rsum[w] = s;
    __syncthreads();
    s = rsum[0] + rsum[1] + rsum[2] + rsum[3];
    const float inv = 1.0f / s;
    us4 o4; o4.x = f2bf(e0 * inv); o4.y = f2bf(e1 * inv);
    o4.z = f2bf(e2 * inv); o4.w = f2bf(e3 * inv);
    *(us4*)(P + row * T_TOK + tid * 4) = o4;
}

// ---------------------------------------------------------------------------
__global__ __launch_bounds__(256)
void convT_kernel(const float* __restrict__ src, us* __restrict__ dst,
                  int K, int N)
{
    __shared__ us tile[32][33];
    const int tn = blockIdx.x, tk = blockIdx.y;
    const int tx = threadIdx.x & 31, ty = threadIdx.x >> 5;
    #pragma unroll
    for (int i = 0; i < 4; ++i) {
        const int r = ty + i * 8;
        tile[r][tx] = f2bf(src[(long)(tk * 32 + r) * N + tn * 32 + tx]);
    }
    __syncthreads();
    #pragma unroll
    for (int i = 0; i < 4; ++i) {
        const int r = ty + i * 8;
        dst[(long)(tn * 32 + r) * K + tk * 32 + tx] = tile[tx][r];
    }
}

// ---------------------------------------------------------------------------
__global__ __launch_bounds__(256)
void wconv32_kernel(const float* __restrict__ Wq, const float* __restrict__ Wk,
                    const float* __restrict__ Wv, const float* __restrict__ W1,
                    const float* __restrict__ W2,
                    us* __restrict__ WqkvT, us* __restrict__ W1T,
                    us* __restrict__ W2T)
{
    __shared__ float tile[32][33];
    const int t = blockIdx.x;
    const float* src; us* dst; int K, N, tk, tn;
    if (t < 3072) {
        const int wsel = t >> 10, tt = t & 1023;
        src = (wsel == 0) ? Wq : (wsel == 1) ? Wk : Wv;
        dst = WqkvT + (long)wsel * (1024 * 1024);
        K = 1024; N = 1024; tk = tt >> 5; tn = tt & 31;
    } else if (t < 7168) {
        const int tt = t - 3072;
        src = W1; dst = W1T; K = 1024; N = 4096; tk = tt >> 7; tn = tt & 127;
    } else {
        const int tt = t - 7168;
        src = W2; dst = W2T; K = 4096; N = 1024; tk = tt >> 5; tn = tt & 31;
    }
    const int r = threadIdx.x >> 3;
    const int c = (threadIdx.x & 7) * 4;
    float4 v = *(const float4*)(src + (long)(tk * 32 + r) * N + tn * 32 + c);
    tile[r][c + 0] = v.x; tile[r][c + 1] = v.y;
    tile[r][c + 2] = v.z; tile[r][c + 3] = v.w;
    __syncthreads();
    const int n  = threadIdx.x >> 3;
    const int k0 = (threadIdx.x & 7) * 4;
    us4 o;
    o.x = f2bf(tile[k0 + 0][n]); o.y = f2bf(tile[k0 + 1][n]);
    o.z = f2bf(tile[k0 + 2][n]); o.w = f2bf(tile[k0 + 3][n]);
    *(us4*)(dst + (long)(tn * 32 + n) * K + tk * 32 + k0) = o;
}

__global__ __launch_bounds__(256)
void cvt_bf16_kernel(const float* __restrict__ X, us* __restrict__ Y)
{
    const long i = ((long)blockIdx.x * 256 + threadIdx.x) * 4;
    float4 v = *(const float4*)(X + i);
    us4 o; o.x = f2bf(v.x); o.y = f2bf(v.y); o.z = f2bf(v.z); o.w = f2bf(v.w);
    *(us4*)(Y + i) = o;
}

// ===========================================================================
// gemm4 (r16): 128x64 tile, BK=64, 4 waves (2Mx2N), 256 thr.
// TWO-buffer LDS (48 KB) -> 3 BLOCKS/CU (12 waves/CU): cross-block TLP
// covers the per-tile vmcnt(0) drain (r4/m114 mechanism) instead of the
// 3-buffer counted-vmcnt pipeline (which capped at 2 blocks/CU).
// Per K-tile: frag ds_reads from buf[cur] -> STAGE(t+1 -> buf^1) (legal:
// buf^1's reads finished before previous barrier) -> barrier -> lgkmcnt(0)
// -> 16 MFMA (setprio) -> vmcnt(0) -> barrier. Grouped-m decode, swizzle
// slot' = slot ^ (row&7) both sides. Numerics identical to r12-r15.
// EPI: 2 C+=v+bias (MLP2) | 3 C+=alpha*v (PV)
//      7 QKV fused N=3072 (cols>=2048 -> V^T) | 8 bf16 v*alpha (QK)
// ===========================================================================
template<int EPI, int GM>
__global__ __launch_bounds__(256, 3)
void gemm4(const us* __restrict__ A, const us* __restrict__ B,
           void* __restrict__ C0, void* __restrict__ C1, void* __restrict__ C2,
           const float* __restrict__ bias,
           int N, int K, long sBz, float alpha)
{
    constexpr int ABUF = 128 * 64;   // 16 KB
    constexpr int BBUF = 64 * 64;    // 8 KB
    __shared__ us As[2 * ABUF];
    __shared__ us Bs[2 * BBUF];

    const int gx = gridDim.x, gy = gridDim.y;
    const int o  = blockIdx.x + gx * blockIdx.y;
    const int nwg = gx * gy;
    const int virt = (nwg & 7) ? o : ((o & 7) * (nwg >> 3) + (o >> 3));
    const int gmw  = GM * gx;
    const int grp  = virt / gmw;
    const int rem  = virt - grp * gmw;
    const int mtile = grp * GM + (rem % GM);
    const int ntile = rem / GM;
    const int m0 = mtile * 128, n0 = ntile * 64;

    const us* Bp = B + (long)(m0 >> 10) * sBz;

    const int tid  = threadIdx.x;
    const int lane = tid & 63, w = tid >> 6;          // 4 waves
    const int srow = lane >> 3, sslot = (lane & 7) ^ srow;
    const int lr = lane & 15, hi = lane >> 4;
    const int wm = (w >> 1) * 64, wn = (w & 1) * 32;

    const us* gA = A + (long)(m0 + w * 32 + srow) * K + sslot * 8;
    const us* gB = Bp + (long)(n0 + w * 16 + srow) * K + sslot * 8;

    f32x4 acc[4][2];
    #pragma unroll
    for (int f = 0; f < 4; ++f)
        #pragma unroll
        for (int g = 0; g < 2; ++g)
            acc[f][g] = (f32x4){0.f, 0.f, 0.f, 0.f};

    const int nk = K >> 6;

    // prologue: stage tile 0 into buf 0, drain, barrier
    #pragma unroll
    for (int j = 0; j < 4; ++j)
        gld_lds16(gA + (long)(j * 8) * K, As + (w * 32 + j * 8) * 64);
    #pragma unroll
    for (int j = 0; j < 2; ++j)
        gld_lds16(gB + (long)(j * 8) * K, Bs + (w * 16 + j * 8) * 64);
    asm volatile("s_waitcnt vmcnt(0)" ::: "memory");
    __builtin_amdgcn_s_barrier();

    for (int t = 0; t < nk; ++t) {
        const int cur = t & 1, nb = cur ^ 1;
        const us* Ac = As + cur * ABUF;
        const us* Bc = Bs + cur * BBUF;
        short8 af[2][4], bg[2][2];
        #pragma unroll
        for (int kk = 0; kk < 2; ++kk) {
            #pragma unroll
            for (int f = 0; f < 4; ++f) {
                const int rr = wm + f * 16 + lr;
                af[kk][f] = *(const short8*)&Ac[rr * 64 + (((kk * 4 + hi) ^ (rr & 7)) * 8)];
            }
            #pragma unroll
            for (int g = 0; g < 2; ++g) {
                const int rn = wn + g * 16 + lr;
                bg[kk][g] = *(const short8*)&Bc[rn * 64 + (((kk * 4 + hi) ^ (rn & 7)) * 8)];
            }
        }
        if (t + 1 < nk) {   // stage next tile into the other buffer
            const int k1 = (t + 1) << 6;
            #pragma unroll
            for (int j = 0; j < 4; ++j)
                gld_lds16(gA + (long)(j * 8) * K + k1,
                          As + nb * ABUF + (w * 32 + j * 8) * 64);
            #pragma unroll
            for (int j = 0; j < 2; ++j)
                gld_lds16(gB + (long)(j * 8) * K + k1,
                          Bs + nb * BBUF + (w * 16 + j * 8) * 64);
        }
        __builtin_amdgcn_s_barrier();
        asm volatile("s_waitcnt lgkmcnt(0)" ::: "memory");
        __builtin_amdgcn_sched_barrier(0);
        __builtin_amdgcn_s_setprio(1);
        #pragma unroll
        for (int kk = 0; kk < 2; ++kk)
            #pragma unroll
            for (int f = 0; f < 4; ++f)
                #pragma unroll
                for (int g = 0; g < 2; ++g)
                    acc[f][g] = __builtin_amdgcn_mfma_f32_16x16x32_bf16(
                        af[kk][f], bg[kk][g], acc[f][g], 0, 0, 0);
        __builtin_amdgcn_s_setprio(0);
        __builtin_amdgcn_sched_barrier(0);
        if (t + 1 < nk) asm volatile("s_waitcnt vmcnt(0)" ::: "memory");
        __builtin_amdgcn_s_barrier();
    }

    // epilogue. D: col = lane&15 (n), row = hi*4 + r (m)
    #pragma unroll
    for (int f = 0; f < 4; ++f) {
        #pragma unroll
        for (int g = 0; g < 2; ++g) {
            const int gm0 = m0 + wm + f * 16 + hi * 4;
            const int gn  = n0 + wn + g * 16 + lr;
            if constexpr (EPI == 7) {
                const int target = gn >> 10, col = gn & 1023;
                if (target == 2) {  // V^T: VT[b][d][t], 4 consecutive t
                    us4 ov;
                    ov.x = f2bf(acc[f][g][0]); ov.y = f2bf(acc[f][g][1]);
                    ov.z = f2bf(acc[f][g][2]); ov.w = f2bf(acc[f][g][3]);
                    *(us4*)&((us*)C2)[(long)(gm0 >> 10) * (T_TOK * D_EMB)
                                      + (long)col * T_TOK + (gm0 & (T_TOK - 1))] = ov;
                } else {
                    us* dst = target ? (us*)C1 : (us*)C0;
                    #pragma unroll
                    for (int r = 0; r < 4; ++r)
                        dst[(long)(gm0 + r) * D_EMB + col] = f2bf(acc[f][g][r]);
                }
            } else if constexpr (EPI == 8) { // bf16 scores, scale folded
                #pragma unroll
                for (int r = 0; r < 4; ++r)
                    ((us*)C0)[(long)(gm0 + r) * N + gn] = f2bf(acc[f][g][r] * alpha);
            } else if constexpr (EPI == 2) {
                #pragma unroll
                for (int r = 0; r < 4; ++r) {
                    float* c = (float*)C0 + (long)(gm0 + r) * N + gn;
                    *c = *c + acc[f][g][r] + bias[gn];
                }
            } else { // EPI == 3
                #pragma unroll
                for (int r = 0; r < 4; ++r) {
                    float* c = (float*)C0 + (long)(gm0 + r) * N + gn;
                    *c = *c + alpha * acc[f][g][r];
                }
            }
        }
    }
}

// ===========================================================================
// gemm8 (r12-proven): 256x128 tile, BK=64, 8 waves, 512 thr, triple-buffer,
// ONE phase/K-tile, counted vmcnt(6) + setprio, grouped-m. MLP1 only.
// ===========================================================================
template<int EPI, int TN, int GM>
__global__ __launch_bounds__(512, 2)
void gemm8(const us* __restrict__ A, const us* __restrict__ B,
           void* __restrict__ C0, void* __restrict__ C1, void* __restrict__ C2,
           const float* __restrict__ bias,
           int N, int K, long sBz, float alpha)
{
    constexpr int FN   = TN / 32;
    constexpr int ABUF = 256 * 64;
    constexpr int BBUF = TN * 64;
    constexpr int BROW = (TN == 128) ? 16 : 8;
    __shared__ us As[3 * ABUF];
    __shared__ us Bs[3 * BBUF];

    const int gx = gridDim.x, gy = gridDim.y;
    const int o  = blockIdx.x + gx * blockIdx.y;
    const int nwg = gx * gy;
    const int virt = (nwg & 7) ? o : ((o & 7) * (nwg >> 3) + (o >> 3));
    const int gmw  = GM * gx;
    const int grp  = virt / gmw;
    const int rem  = virt - grp * gmw;
    const int mtile = grp * GM + (rem % GM);
    const int ntile = rem / GM;
    const int m0 = mtile * 256, n0 = ntile * TN;

    const us* Bp = B + (long)(m0 >> 10) * sBz;

    const int tid  = threadIdx.x;
    const int lane = tid & 63, w = tid >> 6;
    const int srow = lane >> 3, sslot = (lane & 7) ^ srow;
    const int lr = lane & 15, hi = lane >> 4;
    const int wm = (w >> 1) * 64, wn = (w & 1) * (TN / 2);

    const us* gA = A + (long)(m0 + w * 32 + srow) * K + sslot * 8;
    const us* gB = Bp + (long)(n0 + w * BROW + srow) * K + sslot * 8;

    f32x4 acc[4][FN];
    #pragma unroll
    for (int f = 0; f < 4; ++f)
        #pragma unroll
        for (int g = 0; g < FN; ++g)
            acc[f][g] = (f32x4){0.f, 0.f, 0.f, 0.f};

    const int nk = K >> 6;

    #pragma unroll
    for (int tb = 0; tb < 2; ++tb) {
        #pragma unroll
        for (int j = 0; j < 4; ++j)
            gld_lds16(gA + (long)(j * 8) * K + tb * 64,
                      As + tb * ABUF + (w * 32 + j * 8) * 64);
        if constexpr (TN == 128) {
            #pragma unroll
            for (int j = 0; j < 2; ++j)
                gld_lds16(gB + (long)(j * 8) * K + tb * 64,
                          Bs + tb * BBUF + (w * 16 + j * 8) * 64);
        } else {
            gld_lds16(gB + tb * 64, Bs + tb * BBUF + (w * 8) * 64);
        }
    }
    if constexpr (TN == 128) asm volatile("s_waitcnt vmcnt(6)" ::: "memory");
    else                     asm volatile("s_waitcnt vmcnt(5)" ::: "memory");
    __builtin_amdgcn_s_barrier();

    for (int t = 0; t < nk; ++t) {
        const int cur = t % 3, nb = (t + 2) % 3;
        const us* Ac = As + cur * ABUF;
        const us* Bc = Bs + cur * BBUF;
        short8 af[2][4], bg[2][FN];
        #pragma unroll
        for (int kk = 0; kk < 2; ++kk) {
            #pragma unroll
            for (int f = 0; f < 4; ++f) {
                const int rr = wm + f * 16 + lr;
                af[kk][f] = *(const short8*)&Ac[rr * 64 + (((kk * 4 + hi) ^ (rr & 7)) * 8)];
            }
            #pragma unroll
            for (int g = 0; g < FN; ++g) {
                const int rn = wn + g * 16 + lr;
                bg[kk][g] = *(const short8*)&Bc[rn * 64 + (((kk * 4 + hi) ^ (rn & 7)) * 8)];
            }
        }
        if (t + 2 < nk) {
            const int kk2 = (t + 2) << 6;
            #pragma unroll
            for (int j = 0; j < 4; ++j)
                gld_lds16(gA + (long)(j * 8) * K + kk2,
                          As + nb * ABUF + (w * 32 + j * 8) * 64);
            if constexpr (TN == 128) {
                #pragma unroll
                for (int j = 0; j < 2; ++j)
                    gld_lds16(gB + (long)(j * 8) * K + kk2,
                              Bs + nb * BBUF + (w * 16 + j * 8) * 64);
            } else {
                gld_lds16(gB + kk2, Bs + nb * BBUF + (w * 8) * 64);
            }
        }
        __builtin_amdgcn_s_barrier();
        asm volatile("s_waitcnt lgkmcnt(0)" ::: "memory");
        __builtin_amdgcn_sched_barrier(0);
        __builtin_amdgcn_s_setprio(1);
        #pragma unroll
        for (int kk = 0; kk < 2; ++kk)
            #pragma unroll
            for (int f = 0; f < 4; ++f)
                #pragma unroll
                for (int g = 0; g < FN; ++g)
                    acc[f][g] = __builtin_amdgcn_mfma_f32_16x16x32_bf16(
                        af[kk][f], bg[kk][g], acc[f][g], 0, 0, 0);
        __builtin_amdgcn_s_setprio(0);
        __builtin_amdgcn_sched_barrier(0);
        if (t + 2 < nk) {
            if constexpr (TN == 128)
                asm volatile("s_waitcnt vmcnt(6)" ::: "memory");
            else
                asm volatile("s_waitcnt vmcnt(5)" ::: "memory");
        } else if (t + 1 < nk) {
            asm volatile("s_waitcnt vmcnt(0)" ::: "memory");
        }
        __builtin_amdgcn_s_barrier();
    }

    #pragma unroll
    for (int f = 0; f < 4; ++f) {
        #pragma unroll
        for (int g = 0; g < FN; ++g) {
            const int gm0 = m0 + wm + f * 16 + hi * 4;
            const int gn  = n0 + wn + g * 16 + lr;
            if constexpr (EPI == 1) {
                #pragma unroll
                for (int r = 0; r < 4; ++r) {
                    float v = acc[f][g][r] + bias[gn];
                    const float ge = 0.5f * v * (1.0f + erff(v * 0.70710678118f));
                    ((us*)C0)[(long)(gm0 + r) * N + gn] = f2bf(ge);
                }
            } else if constexpr (EPI == 0) {
                #pragma unroll
                for (int r = 0; r < 4; ++r)
                    ((float*)C0)[(long)(gm0 + r) * N + gn] = acc[f][g][r];
            } else { // EPI == 3
                #pragma unroll
                for (int r = 0; r < 4; ++r) {
                    float* c = (float*)C0 + (long)(gm0 + r) * N + gn;
                    *c = *c + alpha * acc[f][g][r];
                }
            }
        }
    }
}

// ---------------------------------------------------------------------------
// 2-buffer 128x64 GEMM, readout slice only (EPI 4).
// ---------------------------------------------------------------------------
template<int EPI, int TN>
__global__ __launch_bounds__(256)
void gemm_bt(const us* __restrict__ A, const us* __restrict__ B0,
             void* __restrict__ C0, const float* __restrict__ bias,
             int M, int N, int K,
             long sAz, long sBz, long sCz, float alpha)
{
    constexpr int FN = TN / 32;
    constexpr int ABUF = 128 * 32;
    constexpr int BBUF = TN * 32;
    __shared__ us As[2 * ABUF];
    __shared__ us Bs[2 * BBUF];

    const int gx = gridDim.x, gy = gridDim.y;
    const int o  = blockIdx.x + gx * blockIdx.y;
    const int nwg = gx * gy;
    const int virt = (nwg & 7) ? o : ((o & 7) * (nwg >> 3) + (o >> 3));
    const int ntile = virt / gy;
    int mtile = virt - ntile * gy;
    if constexpr (EPI == 4) mtile = (mtile / 6) * 8 + 2 + (mtile % 6);
    const int m0 = mtile * 128, n0 = ntile * TN;

    const int tid = threadIdx.x;
    const int l = tid & 63, w = tid >> 6;
    const int wm = (w >> 1) * 64, wn = (w & 1) * (TN / 2);
    const int lr = l & 15, hi = l >> 4;

    const int r0 = tid >> 2;
    const int s0 = (tid & 3) ^ ((r0 >> 1) & 3);
    const us* gA0 = A + (long)(m0 + r0) * K + s0 * 8;
    const us* gA1 = A + (long)(m0 + r0 + 64) * K + s0 * 8;
    const us* gB0 = B0 + (long)(n0 + r0) * K + s0 * 8;
    const int lA0 = w * 512, lA1 = 2048 + w * 512;
    const int lB0 = w * 512;

    f32x4 acc[4][FN];
    #pragma unroll
    for (int f = 0; f < 4; ++f)
        #pragma unroll
        for (int gq = 0; gq < FN; ++gq)
            acc[f][gq] = (f32x4){0.f, 0.f, 0.f, 0.f};

    const int nk = K >> 5;
    gld_lds16(gA0, As + lA0);
    gld_lds16(gA1, As + lA1);
    gld_lds16(gB0, Bs + lB0);
    __syncthreads();

    for (int t = 0; t < nk; ++t) {
        const int cur = t & 1;
        const int aB = (cur ^ 1) * ABUF, bB = (cur ^ 1) * BBUF;
        if (t + 1 < nk) {
            const int k1 = (t + 1) << 5;
            gld_lds16(gA0 + k1, As + aB + lA0);
            gld_lds16(gA1 + k1, As + aB + lA1);
            gld_lds16(gB0 + k1, Bs + bB + lB0);
        }
        const int aC = cur * ABUF, bC = cur * BBUF;
        short8 af[4], bg[FN];
        #pragma unroll
        for (int f = 0; f < 4; ++f) {
            const int rr = wm + f * 16 + lr;
            const int sl = hi ^ ((rr >> 1) & 3);
            af[f] = *(const short8*)&As[aC + rr * 32 + sl * 8];
        }
        #pragma unroll
        for (int gq = 0; gq < FN; ++gq) {
            const int rn = wn + gq * 16 + lr;
            const int sl = hi ^ ((rn >> 1) & 3);
            bg[gq] = *(const short8*)&Bs[bC + rn * 32 + sl * 8];
        }
        #pragma unroll
        for (int f = 0; f < 4; ++f)
            #pragma unroll
            for (int gq = 0; gq < FN; ++gq)
                acc[f][gq] = __builtin_amdgcn_mfma_f32_16x16x32_bf16(
                    af[f], bg[gq], acc[f][gq], 0, 0, 0);
        __syncthreads();
    }

    #pragma unroll
    for (int f = 0; f < 4; ++f) {
        #pragma unroll
        for (int gq = 0; gq < FN; ++gq) {
            #pragma unroll
            for (int r = 0; r < 4; ++r) {
                const int gm = m0 + wm + f * 16 + hi * 4 + r;
                const int gn = n0 + wn + gq * 16 + lr;
                const int tt = gm & (T_TOK - 1);
                ((float*)C0)[(long)((gm >> 10) * T1_TOK + (tt - T2_TOK)) * VCLS + gn]
                    = acc[f][gq][r] + bias[gn];
            }
        }
    }
}

// ---------------------------------------------------------------------------
extern "C" void kernel_launch(void* const* d_in, const int* in_sizes, int n_in,
                              void* d_out, int out_size, void* d_ws, size_t ws_size,
                              hipStream_t stream)
{
    (void)in_sizes; (void)n_in; (void)out_size; (void)ws_size;
    const int*   xt   = (const int*)d_in[0];
    const int*   zi   = (const int*)d_in[1];
    const float* pos  = (const float*)d_in[2];
    const float* temb = (const float*)d_in[3];
    const float* iemb = (const float*)d_in[4];
    const float* ln1g = (const float*)d_in[5];
    const float* ln1b = (const float*)d_in[6];
    const float* Wq   = (const float*)d_in[7];
    const float* Wk   = (const float*)d_in[8];
    const float* Wv   = (const float*)d_in[9];
    const float* ln2g = (const float*)d_in[10];
    const float* ln2b = (const float*)d_in[11];
    const float* W1   = (const float*)d_in[12];
    const float* b1   = (const float*)d_in[13];
    const float* W2   = (const float*)d_in[14];
    const float* b2   = (const float*)d_in[15];
    const float* roW  = (const float*)d_in[16];
    const float* rob  = (const float*)d_in[17];
    float* out = (float*)d_out;

    char* wsb = (char*)d_ws;
    float* H    = (float*)(wsb + 0);                 // 16 MB fp32
    us*    LNb  = (us*)(wsb + 16777216);             // 8 MB bf16
    us*    Sb   = (us*)(wsb + 25165824);             // 8 MB bf16 scores
    us*    Qb   = (us*)(wsb + 41943040);             // 8 MB
    us*    Kb   = (us*)(wsb + 50331648);             // 8 MB
    us*    VT   = (us*)(wsb + 58720256);             // 8 MB (V^T per batch)
    us*    Pb   = (us*)(wsb + 67108864);             // 8 MB
    us*    Hid  = (us*)(wsb + 41943040);             // 32 MB, overlaps Q..P
    us*    WqkvT= (us*)(wsb + 75497472);             // 6 MB (Q,K,V contiguous)
    us*    W1T  = (us*)(wsb + 81788928);             // 8 MB
    us*    W2T  = (us*)(wsb + 90177536);             // 8 MB
    us*    roWT = W1T;
    us*    Hbf  = LNb;

    const long TD = (long)T_TOK * D_EMB;

    embed_kernel<<<4096, 256, 0, stream>>>(xt, zi, pos, temb, iemb, H);

    for (int lyr = 0; lyr < NLAYER; ++lyr) {
        const long dd = (long)lyr * D_EMB * D_EMB;
        const long d1 = (long)lyr * D_EMB * HMLP;
        wconv32_kernel<<<11264, 256, 0, stream>>>(
            Wq + dd, Wk + dd, Wv + dd, W1 + d1, W2 + d1, WqkvT, W1T, W2T);
        ln_kernel<<<4096, 256, 0, stream>>>(H, ln1g + lyr * D_EMB, ln1b + lyr * D_EMB, LNb);
        // QKV fused over N=3072; cols>=2048 -> V^T   [1536 blk, 3/CU]
        gemm4<7, 4><<<dim3(48, 32, 1), 256, 0, stream>>>(
            LNb, WqkvT, Qb, Kb, VT, nullptr, 3072, D_EMB, 0L, 1.f);
        // scores = (Q @ K^T) * 1/32 -> bf16  [512 blk]
        gemm4<8, 4><<<dim3(16, 32, 1), 256, 0, stream>>>(
            Qb, Kb, Sb, nullptr, nullptr, nullptr, T_TOK, D_EMB, TD, 0.03125f);
        softmax_kernel<<<4096, 256, 0, stream>>>(Sb, Pb);
        // H += (1 + 1/D) * P @ V  [512 blk]
        gemm4<3, 4><<<dim3(16, 32, 1), 256, 0, stream>>>(
            Pb, VT, H, nullptr, nullptr, nullptr, D_EMB, T_TOK, TD,
            1.0f + 1.0f / (float)D_EMB);
        ln_kernel<<<4096, 256, 0, stream>>>(H, ln2g + lyr * D_EMB, ln2b + lyr * D_EMB, LNb);
        // hidden = gelu(LN @ W1 + b1) -> bf16  [gemm8 TN=128]
        gemm8<1, 128, 4><<<dim3(32, 16, 1), 512, 0, stream>>>(
            LNb, W1T, Hid, nullptr, nullptr, b1 + (long)lyr * HMLP,
            HMLP, D_EMB, 0L, 1.f);
        // H += hidden @ W2 + b2  [512 blk]
        gemm4<2, 4><<<dim3(16, 32, 1), 256, 0, stream>>>(
            Hid, W2T, H, nullptr, nullptr, b2 + (long)lyr * D_EMB,
            D_EMB, HMLP, 0L, 1.f);
    }
    // readout: out = (H @ ro_W + ro_b)[:, T2:, :]
    cvt_bf16_kernel<<<4096, 256, 0, stream>>>(H, Hbf);
    convT_kernel<<<dim3(16, 32), 256, 0, stream>>>(roW, roWT, D_EMB, VCLS);
    gemm_bt<4, 64><<<dim3(8, 24, 1), 256, 0, stream>>>(
        Hbf, roWT, out, rob, 4096, VCLS, D_EMB, 0L, 0L, 0L, 1.f);
}

// Round 17
// 2514.423 us; speedup vs baseline: 1.0214x; 1.0214x over previous
//
#include <hip/hip_runtime.h>
#include <hip/hip_bf16.h>
#include <math.h>

#define D_EMB  1024
#define T_TOK  1024
#define T1_TOK 768
#define T2_TOK 256
#define HMLP   4096
#define NLAYER 12
#define VCLS   512

typedef __attribute__((ext_vector_type(8))) short          short8; // 8 bf16
typedef __attribute__((ext_vector_type(4))) float          f32x4;
typedef __attribute__((ext_vector_type(4))) unsigned short us4;
typedef unsigned short us;

__device__ __forceinline__ us f2bf(float f) {
    union { float f; unsigned int u; } c; c.f = f;
    unsigned int u = c.u;
    return (us)((u + 0x7FFFu + ((u >> 16) & 1u)) >> 16); // RNE
}

__device__ __forceinline__ float bf2f(us u) {
    union { unsigned int i; float f; } c; c.i = ((unsigned int)u) << 16;
    return c.f;
}

__device__ __forceinline__ void gld_lds16(const us* g, us* l) {
    __builtin_amdgcn_global_load_lds(
        (__attribute__((address_space(1))) void*)g,
        (__attribute__((address_space(3))) void*)l, 16, 0, 0);
}

// ---------------------------------------------------------------------------
__global__ __launch_bounds__(256)
void embed_kernel(const int* __restrict__ xt, const int* __restrict__ zi,
                  const float* __restrict__ pos, const float* __restrict__ temb,
                  const float* __restrict__ iemb, float* __restrict__ H)
{
    const long idx = (long)blockIdx.x * 256 + threadIdx.x;
    const long e   = idx * 4;
    const int  dd  = (int)(e & (D_EMB - 1));
    const long bt  = e >> 10;
    const int  t   = (int)(bt & (T_TOK - 1));
    const int  b   = (int)(bt >> 10);
    const float* src;
    if (t < T2_TOK) src = iemb + (long)zi[b * T2_TOK + t] * D_EMB + dd;
    else            src = temb + (long)xt[b * T1_TOK + (t - T2_TOK)] * D_EMB + dd;
    float4 sv = *(const float4*)src;
    float4 pv = *(const float4*)(pos + (long)t * D_EMB + dd);
    float4 o; o.x = sv.x + pv.x; o.y = sv.y + pv.y; o.z = sv.z + pv.z; o.w = sv.w + pv.w;
    *(float4*)(H + e) = o;
}

// ---------------------------------------------------------------------------
__global__ __launch_bounds__(256)
void ln_kernel(const float* __restrict__ X, const float* __restrict__ g,
               const float* __restrict__ b, us* __restrict__ Y)
{
    const long row = blockIdx.x;
    const int  tid = threadIdx.x;
    float4 v = *(const float4*)(X + row * D_EMB + tid * 4);
    float s = v.x + v.y + v.z + v.w;
    float q = v.x*v.x + v.y*v.y + v.z*v.z + v.w*v.w;
    #pragma unroll
    for (int o = 32; o >= 1; o >>= 1) { s += __shfl_down(s, o); q += __shfl_down(q, o); }
    __shared__ float rs[4], rq[4];
    const int w = tid >> 6;
    if ((tid & 63) == 0) { rs[w] = s; rq[w] = q; }
    __syncthreads();
    s = rs[0] + rs[1] + rs[2] + rs[3];
    q = rq[0] + rq[1] + rq[2] + rq[3];
    const float mean = s * (1.0f / D_EMB);
    const float var  = q * (1.0f / D_EMB) - mean * mean;
    const float rstd = rsqrtf(var + 1e-5f);
    float4 gg = *(const float4*)(g + tid * 4);
    float4 bb = *(const float4*)(b + tid * 4);
    us4 o;
    o.x = f2bf((v.x - mean) * rstd * gg.x + bb.x);
    o.y = f2bf((v.y - mean) * rstd * gg.y + bb.y);
    o.z = f2bf((v.z - mean) * rstd * gg.z + bb.z);
    o.w = f2bf((v.w - mean) * rstd * gg.w + bb.w);
    *(us4*)(Y + row * D_EMB + tid * 4) = o;
}

// ---------------------------------------------------------------------------
__global__ __launch_bounds__(256)
void softmax_kernel(const us* __restrict__ S, us* __restrict__ P)
{
    const long row = blockIdx.x;
    const int  tid = threadIdx.x;
    us4 v = *(const us4*)(S + row * T_TOK + tid * 4);
    float a = bf2f(v.x), b = bf2f(v.y), c = bf2f(v.z), d = bf2f(v.w);
    float mx = fmaxf(fmaxf(a, b), fmaxf(c, d));
    #pragma unroll
    for (int o = 32; o >= 1; o >>= 1) mx = fmaxf(mx, __shfl_down(mx, o));
    __shared__ float rm[4], rsum[4];
    const int w = tid >> 6;
    if ((tid & 63) == 0) rm[w] = mx;
    __syncthreads();
    mx = fmaxf(fmaxf(rm[0], rm[1]), fmaxf(rm[2], rm[3]));
    float e0 = expf(a - mx), e1 = expf(b - mx), e2 = expf(c - mx), e3 = expf(d - mx);
    float s = e0 + e1 + e2 + e3;
    #pragma unroll
    for (int o = 32; o >= 1; o >>= 1) s += __shfl_down(s, o);
    if ((tid & 63) == 0) rsum[w] = s;
    __syncthreads();
    s = rsum[0] + rsum[1] + rsum[2] + rsum[3];
    const float inv = 1.0f / s;
    us4 o4; o4.x = f2bf(e0 * inv); o4.y = f2bf(e1 * inv);
    o4.z = f2bf(e2 * inv); o4.w = f2bf(e3 * inv);
    *(us4*)(P + row * T_TOK + tid * 4) = o4;
}

// ---------------------------------------------------------------------------
__global__ __launch_bounds__(256)
void convT_kernel(const float* __restrict__ src, us* __restrict__ dst,
                  int K, int N)
{
    __shared__ us tile[32][33];
    const int tn = blockIdx.x, tk = blockIdx.y;
    const int tx = threadIdx.x & 31, ty = threadIdx.x >> 5;
    #pragma unroll
    for (int i = 0; i < 4; ++i) {
        const int r = ty + i * 8;
        tile[r][tx] = f2bf(src[(long)(tk * 32 + r) * N + tn * 32 + tx]);
    }
    __syncthreads();
    #pragma unroll
    for (int i = 0; i < 4; ++i) {
        const int r = ty + i * 8;
        dst[(long)(tn * 32 + r) * K + tk * 32 + tx] = tile[tx][r];
    }
}

// ---------------------------------------------------------------------------
__global__ __launch_bounds__(256)
void wconv32_kernel(const float* __restrict__ Wq, const float* __restrict__ Wk,
                    const float* __restrict__ Wv, const float* __restrict__ W1,
                    const float* __restrict__ W2,
                    us* __restrict__ WqkvT, us* __restrict__ W1T,
                    us* __restrict__ W2T)
{
    __shared__ float tile[32][33];
    const int t = blockIdx.x;
    const float* src; us* dst; int K, N, tk, tn;
    if (t < 3072) {
        const int wsel = t >> 10, tt = t & 1023;
        src = (wsel == 0) ? Wq : (wsel == 1) ? Wk : Wv;
        dst = WqkvT + (long)wsel * (1024 * 1024);
        K = 1024; N = 1024; tk = tt >> 5; tn = tt & 31;
    } else if (t < 7168) {
        const int tt = t - 3072;
        src = W1; dst = W1T; K = 1024; N = 4096; tk = tt >> 7; tn = tt & 127;
    } else {
        const int tt = t - 7168;
        src = W2; dst = W2T; K = 4096; N = 1024; tk = tt >> 5; tn = tt & 31;
    }
    const int r = threadIdx.x >> 3;
    const int c = (threadIdx.x & 7) * 4;
    float4 v = *(const float4*)(src + (long)(tk * 32 + r) * N + tn * 32 + c);
    tile[r][c + 0] = v.x; tile[r][c + 1] = v.y;
    tile[r][c + 2] = v.z; tile[r][c + 3] = v.w;
    __syncthreads();
    const int n  = threadIdx.x >> 3;
    const int k0 = (threadIdx.x & 7) * 4;
    us4 o;
    o.x = f2bf(tile[k0 + 0][n]); o.y = f2bf(tile[k0 + 1][n]);
    o.z = f2bf(tile[k0 + 2][n]); o.w = f2bf(tile[k0 + 3][n]);
    *(us4*)(dst + (long)(tn * 32 + n) * K + tk * 32 + k0) = o;
}

// ===========================================================================
// gemm4 (r15-proven): 128x64 tile, BK=64, 4 waves (2Mx2N), 256 thr, 72 KB
// LDS (3-buffer) -> 2 blocks/CU. Triple-buffer, ONE merged phase/K-tile,
// counted vmcnt(6), setprio, grouped-m decode, swizzle both sides.
// [r16 A/B: 2-buffer/3-per-CU with vmcnt(0) drain was +52us — reverted]
// EPI: 2 C+=v+bias (MLP2) | 3 C+=alpha*v (PV)
//      7 QKV fused N=3072 (cols>=2048 -> V^T) | 8 bf16 v*alpha (QK)
//      9 C+=v+bias AND bf16 dual store (final-layer MLP2, fuses cvt_bf16)
// ===========================================================================
template<int EPI, int GM>
__global__ __launch_bounds__(256, 2)
void gemm4(const us* __restrict__ A, const us* __restrict__ B,
           void* __restrict__ C0, void* __restrict__ C1, void* __restrict__ C2,
           const float* __restrict__ bias,
           int N, int K, long sBz, float alpha)
{
    constexpr int ABUF = 128 * 64;   // 16 KB
    constexpr int BBUF = 64 * 64;    // 8 KB
    __shared__ us As[3 * ABUF];
    __shared__ us Bs[3 * BBUF];

    const int gx = gridDim.x, gy = gridDim.y;
    const int o  = blockIdx.x + gx * blockIdx.y;
    const int nwg = gx * gy;
    const int virt = (nwg & 7) ? o : ((o & 7) * (nwg >> 3) + (o >> 3));
    const int gmw  = GM * gx;
    const int grp  = virt / gmw;
    const int rem  = virt - grp * gmw;
    const int mtile = grp * GM + (rem % GM);
    const int ntile = rem / GM;
    const int m0 = mtile * 128, n0 = ntile * 64;

    const us* Bp = B + (long)(m0 >> 10) * sBz;

    const int tid  = threadIdx.x;
    const int lane = tid & 63, w = tid >> 6;          // 4 waves
    const int srow = lane >> 3, sslot = (lane & 7) ^ srow;
    const int lr = lane & 15, hi = lane >> 4;
    const int wm = (w >> 1) * 64, wn = (w & 1) * 32;

    const us* gA = A + (long)(m0 + w * 32 + srow) * K + sslot * 8;
    const us* gB = Bp + (long)(n0 + w * 16 + srow) * K + sslot * 8;

    f32x4 acc[4][2];
    #pragma unroll
    for (int f = 0; f < 4; ++f)
        #pragma unroll
        for (int g = 0; g < 2; ++g)
            acc[f][g] = (f32x4){0.f, 0.f, 0.f, 0.f};

    const int nk = K >> 6;

    #pragma unroll
    for (int tb = 0; tb < 2; ++tb) {
        #pragma unroll
        for (int j = 0; j < 4; ++j)
            gld_lds16(gA + (long)(j * 8) * K + tb * 64,
                      As + tb * ABUF + (w * 32 + j * 8) * 64);
        #pragma unroll
        for (int j = 0; j < 2; ++j)
            gld_lds16(gB + (long)(j * 8) * K + tb * 64,
                      Bs + tb * BBUF + (w * 16 + j * 8) * 64);
    }
    asm volatile("s_waitcnt vmcnt(6)" ::: "memory");
    __builtin_amdgcn_s_barrier();

    for (int t = 0; t < nk; ++t) {
        const int cur = t % 3, nb = (t + 2) % 3;
        const us* Ac = As + cur * ABUF;
        const us* Bc = Bs + cur * BBUF;
        short8 af[2][4], bg[2][2];
        #pragma unroll
        for (int kk = 0; kk < 2; ++kk) {
            #pragma unroll
            for (int f = 0; f < 4; ++f) {
                const int rr = wm + f * 16 + lr;
                af[kk][f] = *(const short8*)&Ac[rr * 64 + (((kk * 4 + hi) ^ (rr & 7)) * 8)];
            }
            #pragma unroll
            for (int g = 0; g < 2; ++g) {
                const int rn = wn + g * 16 + lr;
                bg[kk][g] = *(const short8*)&Bc[rn * 64 + (((kk * 4 + hi) ^ (rn & 7)) * 8)];
            }
        }
        if (t + 2 < nk) {
            const int kk2 = (t + 2) << 6;
            #pragma unroll
            for (int j = 0; j < 4; ++j)
                gld_lds16(gA + (long)(j * 8) * K + kk2,
                          As + nb * ABUF + (w * 32 + j * 8) * 64);
            #pragma unroll
            for (int j = 0; j < 2; ++j)
                gld_lds16(gB + (long)(j * 8) * K + kk2,
                          Bs + nb * BBUF + (w * 16 + j * 8) * 64);
        }
        __builtin_amdgcn_s_barrier();
        asm volatile("s_waitcnt lgkmcnt(0)" ::: "memory");
        __builtin_amdgcn_sched_barrier(0);
        __builtin_amdgcn_s_setprio(1);
        #pragma unroll
        for (int kk = 0; kk < 2; ++kk)
            #pragma unroll
            for (int f = 0; f < 4; ++f)
                #pragma unroll
                for (int g = 0; g < 2; ++g)
                    acc[f][g] = __builtin_amdgcn_mfma_f32_16x16x32_bf16(
                        af[kk][f], bg[kk][g], acc[f][g], 0, 0, 0);
        __builtin_amdgcn_s_setprio(0);
        __builtin_amdgcn_sched_barrier(0);
        if (t + 2 < nk)      asm volatile("s_waitcnt vmcnt(6)" ::: "memory");
        else if (t + 1 < nk) asm volatile("s_waitcnt vmcnt(0)" ::: "memory");
        __builtin_amdgcn_s_barrier();
    }

    // epilogue. D: col = lane&15 (n), row = hi*4 + r (m)
    #pragma unroll
    for (int f = 0; f < 4; ++f) {
        #pragma unroll
        for (int g = 0; g < 2; ++g) {
            const int gm0 = m0 + wm + f * 16 + hi * 4;
            const int gn  = n0 + wn + g * 16 + lr;
            if constexpr (EPI == 7) {
                const int target = gn >> 10, col = gn & 1023;
                if (target == 2) {  // V^T: VT[b][d][t], 4 consecutive t
                    us4 ov;
                    ov.x = f2bf(acc[f][g][0]); ov.y = f2bf(acc[f][g][1]);
                    ov.z = f2bf(acc[f][g][2]); ov.w = f2bf(acc[f][g][3]);
                    *(us4*)&((us*)C2)[(long)(gm0 >> 10) * (T_TOK * D_EMB)
                                      + (long)col * T_TOK + (gm0 & (T_TOK - 1))] = ov;
                } else {
                    us* dst = target ? (us*)C1 : (us*)C0;
                    #pragma unroll
                    for (int r = 0; r < 4; ++r)
                        dst[(long)(gm0 + r) * D_EMB + col] = f2bf(acc[f][g][r]);
                }
            } else if constexpr (EPI == 8) { // bf16 scores, scale folded
                #pragma unroll
                for (int r = 0; r < 4; ++r)
                    ((us*)C0)[(long)(gm0 + r) * N + gn] = f2bf(acc[f][g][r] * alpha);
            } else if constexpr (EPI == 2) {
                #pragma unroll
                for (int r = 0; r < 4; ++r) {
                    float* c = (float*)C0 + (long)(gm0 + r) * N + gn;
                    *c = *c + acc[f][g][r] + bias[gn];
                }
            } else if constexpr (EPI == 9) { // MLP2 final: fp32 RMW + bf16 copy
                #pragma unroll
                for (int r = 0; r < 4; ++r) {
                    const long idx = (long)(gm0 + r) * N + gn;
                    float* c = (float*)C0 + idx;
                    const float nv = *c + acc[f][g][r] + bias[gn];
                    *c = nv;
                    ((us*)C1)[idx] = f2bf(nv);
                }
            } else { // EPI == 3
                #pragma unroll
                for (int r = 0; r < 4; ++r) {
                    float* c = (float*)C0 + (long)(gm0 + r) * N + gn;
                    *c = *c + alpha * acc[f][g][r];
                }
            }
        }
    }
}

// ===========================================================================
// gemm8 (r12-proven): 256x128 tile, BK=64, 8 waves, 512 thr, triple-buffer,
// ONE phase/K-tile, counted vmcnt(6) + setprio, grouped-m. MLP1 only.
// ===========================================================================
template<int EPI, int TN, int GM>
__global__ __launch_bounds__(512, 2)
void gemm8(const us* __restrict__ A, const us* __restrict__ B,
           void* __restrict__ C0, void* __restrict__ C1, void* __restrict__ C2,
           const float* __restrict__ bias,
           int N, int K, long sBz, float alpha)
{
    constexpr int FN   = TN / 32;
    constexpr int ABUF = 256 * 64;
    constexpr int BBUF = TN * 64;
    constexpr int BROW = (TN == 128) ? 16 : 8;
    __shared__ us As[3 * ABUF];
    __shared__ us Bs[3 * BBUF];

    const int gx = gridDim.x, gy = gridDim.y;
    const int o  = blockIdx.x + gx * blockIdx.y;
    const int nwg = gx * gy;
    const int virt = (nwg & 7) ? o : ((o & 7) * (nwg >> 3) + (o >> 3));
    const int gmw  = GM * gx;
    const int grp  = virt / gmw;
    const int rem  = virt - grp * gmw;
    const int mtile = grp * GM + (rem % GM);
    const int ntile = rem / GM;
    const int m0 = mtile * 256, n0 = ntile * TN;

    const us* Bp = B + (long)(m0 >> 10) * sBz;

    const int tid  = threadIdx.x;
    const int lane = tid & 63, w = tid >> 6;
    const int srow = lane >> 3, sslot = (lane & 7) ^ srow;
    const int lr = lane & 15, hi = lane >> 4;
    const int wm = (w >> 1) * 64, wn = (w & 1) * (TN / 2);

    const us* gA = A + (long)(m0 + w * 32 + srow) * K + sslot * 8;
    const us* gB = Bp + (long)(n0 + w * BROW + srow) * K + sslot * 8;

    f32x4 acc[4][FN];
    #pragma unroll
    for (int f = 0; f < 4; ++f)
        #pragma unroll
        for (int g = 0; g < FN; ++g)
            acc[f][g] = (f32x4){0.f, 0.f, 0.f, 0.f};

    const int nk = K >> 6;

    #pragma unroll
    for (int tb = 0; tb < 2; ++tb) {
        #pragma unroll
        for (int j = 0; j < 4; ++j)
            gld_lds16(gA + (long)(j * 8) * K + tb * 64,
                      As + tb * ABUF + (w * 32 + j * 8) * 64);
        if constexpr (TN == 128) {
            #pragma unroll
            for (int j = 0; j < 2; ++j)
                gld_lds16(gB + (long)(j * 8) * K + tb * 64,
                          Bs + tb * BBUF + (w * 16 + j * 8) * 64);
        } else {
            gld_lds16(gB + tb * 64, Bs + tb * BBUF + (w * 8) * 64);
        }
    }
    if constexpr (TN == 128) asm volatile("s_waitcnt vmcnt(6)" ::: "memory");
    else                     asm volatile("s_waitcnt vmcnt(5)" ::: "memory");
    __builtin_amdgcn_s_barrier();

    for (int t = 0; t < nk; ++t) {
        const int cur = t % 3, nb = (t + 2) % 3;
        const us* Ac = As + cur * ABUF;
        const us* Bc = Bs + cur * BBUF;
        short8 af[2][4], bg[2][FN];
        #pragma unroll
        for (int kk = 0; kk < 2; ++kk) {
            #pragma unroll
            for (int f = 0; f < 4; ++f) {
                const int rr = wm + f * 16 + lr;
                af[kk][f] = *(const short8*)&Ac[rr * 64 + (((kk * 4 + hi) ^ (rr & 7)) * 8)];
            }
            #pragma unroll
            for (int g = 0; g < FN; ++g) {
                const int rn = wn + g * 16 + lr;
                bg[kk][g] = *(const short8*)&Bc[rn * 64 + (((kk * 4 + hi) ^ (rn & 7)) * 8)];
            }
        }
        if (t + 2 < nk) {
            const int kk2 = (t + 2) << 6;
            #pragma unroll
            for (int j = 0; j < 4; ++j)
                gld_lds16(gA + (long)(j * 8) * K + kk2,
                          As + nb * ABUF + (w * 32 + j * 8) * 64);
            if constexpr (TN == 128) {
                #pragma unroll
                for (int j = 0; j < 2; ++j)
                    gld_lds16(gB + (long)(j * 8) * K + kk2,
                              Bs + nb * BBUF + (w * 16 + j * 8) * 64);
            } else {
                gld_lds16(gB + kk2, Bs + nb * BBUF + (w * 8) * 64);
            }
        }
        __builtin_amdgcn_s_barrier();
        asm volatile("s_waitcnt lgkmcnt(0)" ::: "memory");
        __builtin_amdgcn_sched_barrier(0);
        __builtin_amdgcn_s_setprio(1);
        #pragma unroll
        for (int kk = 0; kk < 2; ++kk)
            #pragma unroll
            for (int f = 0; f < 4; ++f)
                #pragma unroll
                for (int g = 0; g < FN; ++g)
                    acc[f][g] = __builtin_amdgcn_mfma_f32_16x16x32_bf16(
                        af[kk][f], bg[kk][g], acc[f][g], 0, 0, 0);
        __builtin_amdgcn_s_setprio(0);
        __builtin_amdgcn_sched_barrier(0);
        if (t + 2 < nk) {
            if constexpr (TN == 128)
                asm volatile("s_waitcnt vmcnt(6)" ::: "memory");
            else
                asm volatile("s_waitcnt vmcnt(5)" ::: "memory");
        } else if (t + 1 < nk) {
            asm volatile("s_waitcnt vmcnt(0)" ::: "memory");
        }
        __builtin_amdgcn_s_barrier();
    }

    #pragma unroll
    for (int f = 0; f < 4; ++f) {
        #pragma unroll
        for (int g = 0; g < FN; ++g) {
            const int gm0 = m0 + wm + f * 16 + hi * 4;
            const int gn  = n0 + wn + g * 16 + lr;
            if constexpr (EPI == 1) {
                #pragma unroll
                for (int r = 0; r < 4; ++r) {
                    float v = acc[f][g][r] + bias[gn];
                    const float ge = 0.5f * v * (1.0f + erff(v * 0.70710678118f));
                    ((us*)C0)[(long)(gm0 + r) * N + gn] = f2bf(ge);
                }
            } else if constexpr (EPI == 0) {
                #pragma unroll
                for (int r = 0; r < 4; ++r)
                    ((float*)C0)[(long)(gm0 + r) * N + gn] = acc[f][g][r];
            } else { // EPI == 3
                #pragma unroll
                for (int r = 0; r < 4; ++r) {
                    float* c = (float*)C0 + (long)(gm0 + r) * N + gn;
                    *c = *c + alpha * acc[f][g][r];
                }
            }
        }
    }
}

// ---------------------------------------------------------------------------
// 2-buffer 128x64 GEMM, readout slice only (EPI 4).
// ---------------------------------------------------------------------------
template<int EPI, int TN>
__global__ __launch_bounds__(256)
void gemm_bt(const us* __restrict__ A, const us* __restrict__ B0,
             void* __restrict__ C0, const float* __restrict__ bias,
             int M, int N, int K,
             long sAz, long sBz, long sCz, float alpha)
{
    constexpr int FN = TN / 32;
    constexpr int ABUF = 128 * 32;
    constexpr int BBUF = TN * 32;
    __shared__ us As[2 * ABUF];
    __shared__ us Bs[2 * BBUF];

    const int gx = gridDim.x, gy = gridDim.y;
    const int o  = blockIdx.x + gx * blockIdx.y;
    const int nwg = gx * gy;
    const int virt = (nwg & 7) ? o : ((o & 7) * (nwg >> 3) + (o >> 3));
    const int ntile = virt / gy;
    int mtile = virt - ntile * gy;
    if constexpr (EPI == 4) mtile = (mtile / 6) * 8 + 2 + (mtile % 6);
    const int m0 = mtile * 128, n0 = ntile * TN;

    const int tid = threadIdx.x;
    const int l = tid & 63, w = tid >> 6;
    const int wm = (w >> 1) * 64, wn = (w & 1) * (TN / 2);
    const int lr = l & 15, hi = l >> 4;

    const int r0 = tid >> 2;
    const int s0 = (tid & 3) ^ ((r0 >> 1) & 3);
    const us* gA0 = A + (long)(m0 + r0) * K + s0 * 8;
    const us* gA1 = A + (long)(m0 + r0 + 64) * K + s0 * 8;
    const us* gB0 = B0 + (long)(n0 + r0) * K + s0 * 8;
    const int lA0 = w * 512, lA1 = 2048 + w * 512;
    const int lB0 = w * 512;

    f32x4 acc[4][FN];
    #pragma unroll
    for (int f = 0; f < 4; ++f)
        #pragma unroll
        for (int gq = 0; gq < FN; ++gq)
            acc[f][gq] = (f32x4){0.f, 0.f, 0.f, 0.f};

    const int nk = K >> 5;
    gld_lds16(gA0, As + lA0);
    gld_lds16(gA1, As + lA1);
    gld_lds16(gB0, Bs + lB0);
    __syncthreads();

    for (int t = 0; t < nk; ++t) {
        const int cur = t & 1;
        const int aB = (cur ^ 1) * ABUF, bB = (cur ^ 1) * BBUF;
        if (t + 1 < nk) {
            const int k1 = (t + 1) << 5;
            gld_lds16(gA0 + k1, As + aB + lA0);
            gld_lds16(gA1 + k1, As + aB + lA1);
            gld_lds16(gB0 + k1, Bs + bB + lB0);
        }
        const int aC = cur * ABUF, bC = cur * BBUF;
        short8 af[4], bg[FN];
        #pragma unroll
        for (int f = 0; f < 4; ++f) {
            const int rr = wm + f * 16 + lr;
            const int sl = hi ^ ((rr >> 1) & 3);
            af[f] = *(const short8*)&As[aC + rr * 32 + sl * 8];
        }
        #pragma unroll
        for (int gq = 0; gq < FN; ++gq) {
            const int rn = wn + gq * 16 + lr;
            const int sl = hi ^ ((rn >> 1) & 3);
            bg[gq] = *(const short8*)&Bs[bC + rn * 32 + sl * 8];
        }
        #pragma unroll
        for (int f = 0; f < 4; ++f)
            #pragma unroll
            for (int gq = 0; gq < FN; ++gq)
                acc[f][gq] = __builtin_amdgcn_mfma_f32_16x16x32_bf16(
                    af[f], bg[gq], acc[f][gq], 0, 0, 0);
        __syncthreads();
    }

    #pragma unroll
    for (int f = 0; f < 4; ++f) {
        #pragma unroll
        for (int gq = 0; gq < FN; ++gq) {
            #pragma unroll
            for (int r = 0; r < 4; ++r) {
                const int gm = m0 + wm + f * 16 + hi * 4 + r;
                const int gn = n0 + wn + gq * 16 + lr;
                const int tt = gm & (T_TOK - 1);
                ((float*)C0)[(long)((gm >> 10) * T1_TOK + (tt - T2_TOK)) * VCLS + gn]
                    = acc[f][gq][r] + bias[gn];
            }
        }
    }
}

// ---------------------------------------------------------------------------
extern "C" void kernel_launch(void* const* d_in, const int* in_sizes, int n_in,
                              void* d_out, int out_size, void* d_ws, size_t ws_size,
                              hipStream_t stream)
{
    (void)in_sizes; (void)n_in; (void)out_size; (void)ws_size;
    const int*   xt   = (const int*)d_in[0];
    const int*   zi   = (const int*)d_in[1];
    const float* pos  = (const float*)d_in[2];
    const float* temb = (const float*)d_in[3];
    const float* iemb = (const float*)d_in[4];
    const float* ln1g = (const float*)d_in[5];
    const float* ln1b = (const float*)d_in[6];
    const float* Wq   = (const float*)d_in[7];
    const float* Wk   = (const float*)d_in[8];
    const float* Wv   = (const float*)d_in[9];
    const float* ln2g = (const float*)d_in[10];
    const float* ln2b = (const float*)d_in[11];
    const float* W1   = (const float*)d_in[12];
    const float* b1   = (const float*)d_in[13];
    const float* W2   = (const float*)d_in[14];
    const float* b2   = (const float*)d_in[15];
    const float* roW  = (const float*)d_in[16];
    const float* rob  = (const float*)d_in[17];
    float* out = (float*)d_out;

    char* wsb = (char*)d_ws;
    float* H    = (float*)(wsb + 0);                 // 16 MB fp32
    us*    LNb  = (us*)(wsb + 16777216);             // 8 MB bf16
    us*    Sb   = (us*)(wsb + 25165824);             // 8 MB bf16 scores
    us*    Qb   = (us*)(wsb + 41943040);             // 8 MB
    us*    Kb   = (us*)(wsb + 50331648);             // 8 MB
    us*    VT   = (us*)(wsb + 58720256);             // 8 MB (V^T per batch)
    us*    Pb   = (us*)(wsb + 67108864);             // 8 MB
    us*    Hid  = (us*)(wsb + 41943040);             // 32 MB, overlaps Q..P
    us*    WqkvT= (us*)(wsb + 75497472);             // 6 MB (Q,K,V contiguous)
    us*    W1T  = (us*)(wsb + 81788928);             // 8 MB
    us*    W2T  = (us*)(wsb + 90177536);             // 8 MB
    us*    roWT = W1T;
    us*    Hbf  = LNb;

    const long TD = (long)T_TOK * D_EMB;

    embed_kernel<<<4096, 256, 0, stream>>>(xt, zi, pos, temb, iemb, H);

    for (int lyr = 0; lyr < NLAYER; ++lyr) {
        const long dd = (long)lyr * D_EMB * D_EMB;
        const long d1 = (long)lyr * D_EMB * HMLP;
        wconv32_kernel<<<11264, 256, 0, stream>>>(
            Wq + dd, Wk + dd, Wv + dd, W1 + d1, W2 + d1, WqkvT, W1T, W2T);
        ln_kernel<<<4096, 256, 0, stream>>>(H, ln1g + lyr * D_EMB, ln1b + lyr * D_EMB, LNb);
        // QKV fused over N=3072; cols>=2048 -> V^T   [1536 blk, 2/CU]
        gemm4<7, 4><<<dim3(48, 32, 1), 256, 0, stream>>>(
            LNb, WqkvT, Qb, Kb, VT, nullptr, 3072, D_EMB, 0L, 1.f);
        // scores = (Q @ K^T) * 1/32 -> bf16  [512 blk]
        gemm4<8, 4><<<dim3(16, 32, 1), 256, 0, stream>>>(
            Qb, Kb, Sb, nullptr, nullptr, nullptr, T_TOK, D_EMB, TD, 0.03125f);
        softmax_kernel<<<4096, 256, 0, stream>>>(Sb, Pb);
        // H += (1 + 1/D) * P @ V  [512 blk]
        gemm4<3, 4><<<dim3(16, 32, 1), 256, 0, stream>>>(
            Pb, VT, H, nullptr, nullptr, nullptr, D_EMB, T_TOK, TD,
            1.0f + 1.0f / (float)D_EMB);
        ln_kernel<<<4096, 256, 0, stream>>>(H, ln2g + lyr * D_EMB, ln2b + lyr * D_EMB, LNb);
        // hidden = gelu(LN @ W1 + b1) -> bf16  [gemm8 TN=128]
        gemm8<1, 128, 4><<<dim3(32, 16, 1), 512, 0, stream>>>(
            LNb, W1T, Hid, nullptr, nullptr, b1 + (long)lyr * HMLP,
            HMLP, D_EMB, 0L, 1.f);
        // H += hidden @ W2 + b2  [512 blk]; final layer also emits bf16 H
        if (lyr < NLAYER - 1) {
            gemm4<2, 4><<<dim3(16, 32, 1), 256, 0, stream>>>(
                Hid, W2T, H, nullptr, nullptr, b2 + (long)lyr * D_EMB,
                D_EMB, HMLP, 0L, 1.f);
        } else {
            gemm4<9, 4><<<dim3(16, 32, 1), 256, 0, stream>>>(
                Hid, W2T, H, Hbf, nullptr, b2 + (long)lyr * D_EMB,
                D_EMB, HMLP, 0L, 1.f);
        }
    }
    // readout: out = (H @ ro_W + ro_b)[:, T2:, :]  (Hbf written by last MLP2)
    convT_kernel<<<dim3(16, 32), 256, 0, stream>>>(roW, roWT, D_EMB, VCLS);
    gemm_bt<4, 64><<<dim3(8, 24, 1), 256, 0, stream>>>(
        Hbf, roWT, out, rob, 4096, VCLS, D_EMB, 0L, 0L, 0L, 1.f);
}